// Round 5
// baseline (211.424 us; speedup 1.0000x reference)
//
// TriangleAttention — ROUND 5: k_out fused into k_fused tail (og lives in registers);
// bias layout [h][i][j] for coalesced stores+loads. 3 kernels total.
// B=1, L=256, C=128, H=4, D=32.
// Semantics (identical to passing R2-R4):
//   * logits = (q.k) * sqrt(D)   (reference divides by scale = D^-0.5)
//   * masked (exactly one of src_mask[i],src_mask[j]==0): logits := -1e-9 (NOT -inf)
//   * bias = LN(z)@w_pair at (i_query, j_key), shared over r; stored biasN[h][i][j]
//   * softmax over j, no max-subtraction (logits bounded ~|20| << 88, exp exact in f32)
//   * gate = sigmoid(LN(z)@w_gate + b_gate); out = (gate.*attnout)@w_out + b_out
// ws: WcS bf16 4 heads x [128 rows][128 c] pre-swizzled LDS image @0 (131072 B);
//     WoS bf16 [128 n][128 c] pre-swizzled image @131072 (32768 B); biasN f32[4][256][256] @163840 (1 MB).
// k_fused LDS (156672 B): phase0 zn [256]x256B swz @0 ; steady: Qs[256][40] @0, Ks @20480,
//   Vt [32]x512B swz @40960, P 16 waves x 2048B @57344, Wt dbuf 2x32768 @90112 (buf0 -> WoS for tail),
//   smk @155648 ; tail: og tiles 16 waves x 4096B @0 (Qs/Ks/Vt/P dead).
// MFMA 16x16x32 bf16 maps: A: row=l&15,k=(l>>4)*8+e ; B: col=l&15,k=(l>>4)*8+e ; D: col=l&15,row=(l>>4)*4+reg.

#include <hip/hip_runtime.h>
#include <hip/hip_bf16.h>

#define L_DIM 256
#define C_DIM 128
#define H_DIM 4
#define NPOS (L_DIM * L_DIM)
#define SQRT_D 5.6568542494923806f

typedef float f32x4 __attribute__((ext_vector_type(4)));
typedef short bf16x8 __attribute__((ext_vector_type(8)));
typedef unsigned short ushort8_t __attribute__((ext_vector_type(8)));

__device__ __forceinline__ float bf2f(unsigned short u) {
  return __uint_as_float(((unsigned)u) << 16);
}
__device__ __forceinline__ unsigned short f2bf(float f) {
  unsigned u = __float_as_uint(f);
  unsigned r = u + 0x7fffu + ((u >> 16) & 1u);   // RNE
  return (unsigned short)(r >> 16);
}

// ---------------- K0: weights -> bf16 pre-swizzled LDS images ----------------
// WcS head h, row rr = o*32 + n32 (o: 0=Q,1=K,2=V,3=G), elem c at byte rr*256 + ((2c)^((rr&7)<<4)).
// WoS row n (output col), elem c at byte n*256 + ((2c)^((n&7)<<4)).
__global__ __launch_bounds__(256)
void k_prep(const float* __restrict__ w_qkv, const float* __restrict__ w_gate,
            const float* __restrict__ w_out,
            unsigned short* __restrict__ WcS, unsigned short* __restrict__ WoS) {
  int idx = blockIdx.x * 256 + threadIdx.x;
  if (idx < 4 * 128 * 128) {
    int h = idx >> 14, rem = idx & 16383, rr = rem >> 7, c = rem & 127;
    int o = rr >> 5, n32 = rr & 31;
    float v = (o < 3) ? w_qkv[c * 384 + o * 128 + h * 32 + n32]
                      : w_gate[c * 128 + h * 32 + n32];
    int byte_in_row = (2 * c) ^ ((rr & 7) << 4);
    WcS[h * 16384 + rr * 128 + (byte_in_row >> 1)] = f2bf(v);
  } else if (idx < 4 * 128 * 128 + 128 * 128) {
    int i2 = idx - 65536;
    int n = i2 >> 7, c = i2 & 127;
    int byte_in_row = (2 * c) ^ ((n & 7) << 4);
    WoS[n * 128 + (byte_in_row >> 1)] = f2bf(w_out[c * 128 + n]);
  }
}

// ---------------- K1: LN + pair-bias -> biasN[h][i][j] (natural layout, coalesced) ----------------
__global__ __launch_bounds__(256)
void k_bias(const float* __restrict__ z, const float* __restrict__ ln_g,
            const float* __restrict__ ln_b, const float* __restrict__ w_pair,
            float* __restrict__ biasN) {
  int t = threadIdx.x;
  int p = blockIdx.x * 32 + (t >> 3);
  int lane = t & 7;
  const float* zp = &z[(size_t)p * C_DIM + lane * 16];
  float x[16];
  #pragma unroll
  for (int e = 0; e < 4; e++) {
    float4 v = reinterpret_cast<const float4*>(zp)[e];
    x[e * 4 + 0] = v.x; x[e * 4 + 1] = v.y; x[e * 4 + 2] = v.z; x[e * 4 + 3] = v.w;
  }
  float s = 0.f;
  #pragma unroll
  for (int e = 0; e < 16; e++) s += x[e];
  s += __shfl_xor(s, 1); s += __shfl_xor(s, 2); s += __shfl_xor(s, 4);
  float mu = s * (1.0f / C_DIM);
  float v2 = 0.f;
  #pragma unroll
  for (int e = 0; e < 16; e++) { float d = x[e] - mu; v2 += d * d; }
  v2 += __shfl_xor(v2, 1); v2 += __shfl_xor(v2, 2); v2 += __shfl_xor(v2, 4);
  float rs = rsqrtf(v2 * (1.0f / C_DIM) + 1e-5f);
  float bh[H_DIM] = {};
  #pragma unroll
  for (int e = 0; e < 16; e++) {
    int c = lane * 16 + e;
    float zn = (x[e] - mu) * rs * ln_g[c] + ln_b[c];
    #pragma unroll
    for (int h = 0; h < H_DIM; h++) bh[h] += zn * w_pair[c * H_DIM + h];
  }
  #pragma unroll
  for (int h = 0; h < H_DIM; h++) {
    bh[h] += __shfl_xor(bh[h], 1); bh[h] += __shfl_xor(bh[h], 2); bh[h] += __shfl_xor(bh[h], 4);
  }
  // all 8 lanes hold the full sums; lanes 0-3 store h=lane. biasN[h*NPOS + p] (p = i*256+j).
  if (lane < H_DIM) biasN[lane * NPOS + p] = bh[lane];
}

// ---------------- K2: fused LN + projections + attention + gate + out-projection ----------------
__global__ __launch_bounds__(1024, 4)
void k_fused(const float* __restrict__ z, const int* __restrict__ src_mask,
             const float* __restrict__ ln_g, const float* __restrict__ ln_b,
             const float* __restrict__ b_gate, const unsigned short* __restrict__ WcS,
             const unsigned short* __restrict__ WoS, const float* __restrict__ biasN,
             const float* __restrict__ b_out, float* __restrict__ out) {
  __shared__ __align__(16) char smem[156672];
  char* zn_c = smem;                                       // phase0 only
  unsigned short* Qs = (unsigned short*)(smem);            // [256][40]  (zn dead by then)
  unsigned short* Ks = (unsigned short*)(smem + 20480);    // [256][40]
  char* Vt_c = smem + 40960;                               // [32] x 512B swz
  char* P_c0 = smem + 57344;                               // 16 waves x 2048B
  char* Wt_c = smem + 90112;                               // 2 x 32768 (buf0 -> WoS in tail)
  int*  smk  = (int*)(smem + 155648);

  const int t = threadIdx.x;
  const int wave = t >> 6, lane = t & 63;
  const int l15 = lane & 15, l4 = lane >> 4;
  const int rbase = blockIdx.x * L_DIM;
  const int wrow0 = wave * 16;                             // this wave's 16 query rows
  char* P_c = P_c0 + wave * 2048;                          // [16] rows x 128B swz

  // ---- phase 0: LayerNorm z[r] -> zn (bf16 swz), smk, stage Wt buf0 (head 0) ----
  {
    int ln8 = t & 7;
    #pragma unroll
    for (int pass = 0; pass < 2; ++pass) {
      int pos = pass * 128 + (t >> 3);
      const float* zp = z + ((size_t)(rbase + pos)) * C_DIM + ln8 * 16;
      float x[16];
      #pragma unroll
      for (int e = 0; e < 4; e++) {
        float4 v = reinterpret_cast<const float4*>(zp)[e];
        x[e * 4 + 0] = v.x; x[e * 4 + 1] = v.y; x[e * 4 + 2] = v.z; x[e * 4 + 3] = v.w;
      }
      float s = 0.f;
      #pragma unroll
      for (int e = 0; e < 16; e++) s += x[e];
      s += __shfl_xor(s, 1); s += __shfl_xor(s, 2); s += __shfl_xor(s, 4);
      float mu = s * (1.0f / C_DIM);
      float v2 = 0.f;
      #pragma unroll
      for (int e = 0; e < 16; e++) { float d = x[e] - mu; v2 += d * d; }
      v2 += __shfl_xor(v2, 1); v2 += __shfl_xor(v2, 2); v2 += __shfl_xor(v2, 4);
      float rstd = rsqrtf(v2 * (1.0f / C_DIM) + 1e-5f);
      unsigned short hb[16];
      #pragma unroll
      for (int e = 0; e < 16; e++) {
        int c = ln8 * 16 + e;
        hb[e] = f2bf((x[e] - mu) * rstd * ln_g[c] + ln_b[c]);
      }
      uint4 w0, w1;
      w0.x = hb[0] | ((unsigned)hb[1] << 16);  w0.y = hb[2] | ((unsigned)hb[3] << 16);
      w0.z = hb[4] | ((unsigned)hb[5] << 16);  w0.w = hb[6] | ((unsigned)hb[7] << 16);
      w1.x = hb[8] | ((unsigned)hb[9] << 16);  w1.y = hb[10] | ((unsigned)hb[11] << 16);
      w1.z = hb[12] | ((unsigned)hb[13] << 16); w1.w = hb[14] | ((unsigned)hb[15] << 16);
      int sw = (pos & 7) << 4;
      *(uint4*)(zn_c + pos * 256 + ((ln8 * 32) ^ sw)) = w0;
      *(uint4*)(zn_c + pos * 256 + ((ln8 * 32 + 16) ^ sw)) = w1;
    }
    if (t < 256) smk[t] = src_mask[t];
    const ushort8_t* src = (const ushort8_t*)WcS;
    ushort8_t* dst = (ushort8_t*)Wt_c;
    dst[t] = src[t];
    dst[t + 1024] = src[t + 1024];
  }
  __syncthreads();

  // ---- hoist A-fragments (wave's 16 zn rows, shared across heads/outputs) + mask bits ----
  bf16x8 afr[4];
  {
    int row = wrow0 + l15, sw = (row & 7) << 4;
    #pragma unroll
    for (int kk = 0; kk < 4; kk++)
      afr[kk] = *(const bf16x8*)(zn_c + row * 256 + ((kk * 64 + l4 * 16) ^ sw));
  }
  unsigned mib = 0, mjb = 0;
  #pragma unroll
  for (int q = 0; q < 4; q++)
    if (smk[wrow0 + l4 * 4 + q] == 0) mib |= 1u << q;
  #pragma unroll
  for (int jj = 0; jj < 16; jj++)
    if (smk[(jj >> 2) * 64 + (jj & 3) * 16 + l15] == 0) mjb |= 1u << jj;
  __syncthreads();   // zn reads complete before proj overwrites region

  unsigned og_pk[16];   // packed bf16 og tile: [(h*2+nd)*2 + (q>>1)], low=even q

  for (int h = 0; h < H_DIM; ++h) {
    const char* WtCur = Wt_c + (h & 1) * 32768;
    // T14 split-stage: issue next buffer's global loads now (heads 1-3, then WoS), store after attention
    ushort8_t ld0, ld1;
    {
      const ushort8_t* src = (h < 3) ? (const ushort8_t*)(WcS + (h + 1) * 16384)
                                     : (const ushort8_t*)WoS;
      ld0 = src[t]; ld1 = src[t + 1024];
    }

    // ---- projections: Q,K -> padded LDS ; V -> transposed swz LDS ; G -> regs ----
    f32x4 gacc[2];
    #pragma unroll
    for (int o = 0; o < 4; o++) {
      #pragma unroll
      for (int nt = 0; nt < 2; nt++) {
        f32x4 acc = {0.f, 0.f, 0.f, 0.f};
        #pragma unroll
        for (int kk = 0; kk < 4; kk++) {
          int wr = o * 32 + nt * 16 + l15;
          bf16x8 bfr = *(const bf16x8*)(WtCur + wr * 256 + ((kk * 64 + l4 * 16) ^ ((wr & 7) << 4)));
          acc = __builtin_amdgcn_mfma_f32_16x16x32_bf16(afr[kk], bfr, acc, 0, 0, 0);
        }
        int colb = nt * 16 + l15;
        int rowb = wrow0 + l4 * 4;
        if (o == 0) {
          #pragma unroll
          for (int q = 0; q < 4; q++) Qs[(rowb + q) * 40 + colb] = f2bf(acc[q]);
        } else if (o == 1) {
          #pragma unroll
          for (int q = 0; q < 4; q++) Ks[(rowb + q) * 40 + colb] = f2bf(acc[q]);
        } else if (o == 2) {
          uint2 pv;
          pv.x = f2bf(acc[0]) | ((unsigned)f2bf(acc[1]) << 16);
          pv.y = f2bf(acc[2]) | ((unsigned)f2bf(acc[3]) << 16);
          *(uint2*)(Vt_c + colb * 512 + ((rowb * 2) ^ ((colb & 7) << 4))) = pv;
        } else {
          gacc[nt] = acc;
        }
      }
    }
    __syncthreads();

    // ---- attention (no-max softmax) ----
    bf16x8 qfr = *(const bf16x8*)((const char*)Qs + (wrow0 + l15) * 80 + l4 * 16);
    const float* biasNh = biasN + h * NPOS;
    float s_part[4] = {0.f, 0.f, 0.f, 0.f};
    f32x4 o_acc[2];
    o_acc[0] = (f32x4){0.f, 0.f, 0.f, 0.f};
    o_acc[1] = (f32x4){0.f, 0.f, 0.f, 0.f};

    for (int jb = 0; jb < 4; ++jb) {
      f32x4 sacc[4];
      #pragma unroll
      for (int ji = 0; ji < 4; ji++) {
        int jr = jb * 64 + ji * 16 + l15;
        bf16x8 kfr = *(const bf16x8*)((const char*)Ks + jr * 80 + l4 * 16);
        f32x4 zz = {0.f, 0.f, 0.f, 0.f};
        sacc[ji] = __builtin_amdgcn_mfma_f32_16x16x32_bf16(qfr, kfr, zz, 0, 0, 0);
      }
      #pragma unroll
      for (int ji = 0; ji < 4; ji++) {
        int jcol = jb * 64 + ji * 16 + l15;
        bool mjz = (mjb >> (jb * 4 + ji)) & 1u;
        #pragma unroll
        for (int q = 0; q < 4; q++) {
          // coalesced: 16 lanes (l15) read 64B contiguous at row (wrow0+l4*4+q)
          float bb = biasNh[(wrow0 + l4 * 4 + q) * L_DIM + jcol];
          float sv = sacc[ji][q] * SQRT_D + bb;
          bool miz = (mib >> q) & 1u;
          if (miz != mjz) sv = -1e-9f;
          float p = __expf(sv);
          s_part[q] += p;
          int il = l4 * 4 + q, jl = ji * 16 + l15;
          *(unsigned short*)(P_c + il * 128 + ((jl * 2) ^ ((il & 7) << 4))) = f2bf(p);
        }
      }
      #pragma unroll
      for (int kk = 0; kk < 2; kk++) {
        bf16x8 pfr = *(const bf16x8*)(P_c + l15 * 128 + ((kk * 64 + l4 * 16) ^ ((l15 & 7) << 4)));
        #pragma unroll
        for (int nd = 0; nd < 2; nd++) {
          int vr = nd * 16 + l15;
          bf16x8 vfr = *(const bf16x8*)(Vt_c + vr * 512 +
                                        ((jb * 128 + kk * 64 + l4 * 16) ^ ((vr & 7) << 4)));
          o_acc[nd] = __builtin_amdgcn_mfma_f32_16x16x32_bf16(pfr, vfr, o_acc[nd], 0, 0, 0);
        }
      }
    }

    // row sums
    #pragma unroll
    for (int q = 0; q < 4; q++) {
      float s = s_part[q];
      s += __shfl_xor(s, 1); s += __shfl_xor(s, 2);
      s += __shfl_xor(s, 4); s += __shfl_xor(s, 8);
      s_part[q] = s;
    }

    // ---- epilogue: O/sum, gate -> packed bf16 registers (no global write) ----
    #pragma unroll
    for (int nd = 0; nd < 2; nd++) {
      int c = h * 32 + nd * 16 + l15;
      float bg = b_gate[c];
      unsigned short pk[4];
      #pragma unroll
      for (int q = 0; q < 4; q++) {
        float g = 1.0f / (1.0f + __expf(-(gacc[nd][q] + bg)));
        pk[q] = f2bf(o_acc[nd][q] * (1.0f / s_part[q]) * g);
      }
      og_pk[(h * 2 + nd) * 2 + 0] = pk[0] | ((unsigned)pk[1] << 16);
      og_pk[(h * 2 + nd) * 2 + 1] = pk[2] | ((unsigned)pk[3] << 16);
    }

    // complete next staging (head h+1 weights, or WoS for the tail)
    {
      ushort8_t* dst = (ushort8_t*)(Wt_c + ((h + 1) & 1) * 32768);
      dst[t] = ld0;
      dst[t + 1024] = ld1;
    }
    __syncthreads();
  }

  // ---- tail: out = og @ w_out + b_out (per-wave og tile; WoS staged in Wt buf0) ----
  // og tiles overwrite Qs/Ks/Vt/P (all dead); barrier above ensures no wave still reads them.
  {
    char* ogt = smem + wave * 4096;   // [16 rows] x 256B swz
    #pragma unroll
    for (int h2 = 0; h2 < 4; h2++) {
      #pragma unroll
      for (int nd = 0; nd < 2; nd++) {
        int c2 = h2 * 32 + nd * 16 + l15;
        unsigned ua = og_pk[(h2 * 2 + nd) * 2 + 0];
        unsigned ub = og_pk[(h2 * 2 + nd) * 2 + 1];
        int r0 = l4 * 4;
        *(unsigned short*)(ogt + (r0 + 0) * 256 + ((2 * c2) ^ (((r0 + 0) & 7) << 4))) = (unsigned short)(ua & 0xffff);
        *(unsigned short*)(ogt + (r0 + 1) * 256 + ((2 * c2) ^ (((r0 + 1) & 7) << 4))) = (unsigned short)(ua >> 16);
        *(unsigned short*)(ogt + (r0 + 2) * 256 + ((2 * c2) ^ (((r0 + 2) & 7) << 4))) = (unsigned short)(ub & 0xffff);
        *(unsigned short*)(ogt + (r0 + 3) * 256 + ((2 * c2) ^ (((r0 + 3) & 7) << 4))) = (unsigned short)(ub >> 16);
      }
    }
    // same-wave RAW on LDS: compiler inserts lgkmcnt wait
    bf16x8 afr2[4];
    {
      int row = l15, sw = (row & 7) << 4;
      #pragma unroll
      for (int kk = 0; kk < 4; kk++)
        afr2[kk] = *(const bf16x8*)(ogt + row * 256 + ((kk * 64 + l4 * 16) ^ sw));
    }
    const char* WoS_c = Wt_c;   // buf0
    #pragma unroll
    for (int nt = 0; nt < 8; nt++) {
      f32x4 a2 = {0.f, 0.f, 0.f, 0.f};
      #pragma unroll
      for (int kk = 0; kk < 4; kk++) {
        int wr = nt * 16 + l15;
        bf16x8 bfr = *(const bf16x8*)(WoS_c + wr * 256 + ((kk * 64 + l4 * 16) ^ ((wr & 7) << 4)));
        a2 = __builtin_amdgcn_mfma_f32_16x16x32_bf16(afr2[kk], bfr, a2, 0, 0, 0);
      }
      int n = nt * 16 + l15;
      float bo = b_out[n];
      #pragma unroll
      for (int q = 0; q < 4; q++)
        out[(size_t)(rbase + wrow0 + l4 * 4 + q) * C_DIM + n] = a2[q] + bo;
    }
  }
}

// ---------------- launch ----------------
extern "C" void kernel_launch(void* const* d_in, const int* in_sizes, int n_in,
                              void* d_out, int out_size, void* d_ws, size_t ws_size,
                              hipStream_t stream) {
  const float* z      = (const float*)d_in[0];
  const int*   smask  = (const int*)  d_in[1];
  const float* ln_g   = (const float*)d_in[2];
  const float* ln_b   = (const float*)d_in[3];
  const float* w_qkv  = (const float*)d_in[4];
  const float* w_pair = (const float*)d_in[5];
  const float* w_gate = (const float*)d_in[6];
  const float* b_gate = (const float*)d_in[7];
  const float* w_out  = (const float*)d_in[8];
  const float* b_out  = (const float*)d_in[9];
  float* out = (float*)d_out;

  char* ws = (char*)d_ws;
  unsigned short* WcS   = (unsigned short*)(ws);            // 131072 B (pre-swizzled per-head images)
  unsigned short* WoS   = (unsigned short*)(ws + 131072);   // 32768 B (pre-swizzled)
  float*          biasN = (float*)(ws + 163840);            // 1,048,576 B  [h][i][j]
  (void)ws_size; (void)in_sizes; (void)n_in; (void)out_size;

  k_prep<<<dim3(320), dim3(256), 0, stream>>>(w_qkv, w_gate, w_out, WcS, WoS);
  k_bias<<<dim3(NPOS / 32), dim3(256), 0, stream>>>(z, ln_g, ln_b, w_pair, biasN);
  k_fused<<<dim3(L_DIM), dim3(1024), 0, stream>>>(z, smask, ln_g, ln_b, b_gate, WcS, WoS,
                                                  biasN, b_out, out);
}